// Round 1
// baseline (656.410 us; speedup 1.0000x reference)
//
#include <hip/hip_runtime.h>

#define Bn 8
#define Cin 3
#define Hh 512
#define Ww 512
#define PADc 10
#define KS 21
#define TILE 64
#define TROWS 84           // TILE + 2*PAD
#define XSTRIDE 96         // floats per LDS row = 24 float4 groups (swizzle domain)
#define KSTRIDE 24
#define NPAIR 24

// distinct-conv dedup: out channel o uses input channel o/22 and kernel o/3.
// distinct pairs p=0..23: c = p>>3, k = p - c. Duplicate out channels
// [max(3k,22c), min(3k+2, 22c+21)] all get the same result.

__global__ __launch_bounds__(256) void gcm_conv(
    const float* __restrict__ x,
    const float* __restrict__ wgt,
    const float* __restrict__ bw,
    float* __restrict__ out)
{
    __shared__ __align__(16) float sx[TROWS * XSTRIDE];
    __shared__ __align__(16) float sk[KS * KSTRIDE];

    const int tid = threadIdx.x;
    const int bx = blockIdx.x, by = blockIdx.y, bz = blockIdx.z;
    const int b = bz / NPAIR;
    const int p = bz - b * NPAIR;
    const int c = p >> 3;
    const int k = p - c;

    // ---- stage mixed kernel: K = sum_g w[b,g,k] * BW[g,k]
    const float w0 = wgt[(b*4 + 0)*22 + k];
    const float w1 = wgt[(b*4 + 1)*22 + k];
    const float w2 = wgt[(b*4 + 2)*22 + k];
    const float w3 = wgt[(b*4 + 3)*22 + k];
    for (int idx = tid; idx < KS*KSTRIDE; idx += 256) {
        int r  = idx / KSTRIDE;
        int cc = idx - r*KSTRIDE;
        float v = 0.f;
        if (cc < KS) {
            int o = r*KS + cc;
            v = w0*bw[(0*22 + k)*441 + o] + w1*bw[(1*22 + k)*441 + o]
              + w2*bw[(2*22 + k)*441 + o] + w3*bw[(3*22 + k)*441 + o];
        }
        sk[idx] = v;
    }

    // ---- stage x tile (with halo, zero-padded, swizzled columns)
    const int gx0 = bx*TILE - PADc;
    const int gy0 = by*TILE - PADc;
    const float* xc = x + ((size_t)(b*Cin + c) * Hh) * Ww;
    for (int idx = tid; idx < TROWS*TROWS; idx += 256) {
        int r  = idx / TROWS;
        int cc = idx - r*TROWS;
        int gy = gy0 + r, gx = gx0 + cc;
        float v = 0.f;
        if ((unsigned)gy < (unsigned)Hh && (unsigned)gx < (unsigned)Ww)
            v = xc[gy*Ww + gx];
        int c4 = (cc >> 2) + 3*((r >> 1) & 7);
        if (c4 >= 24) c4 -= 24;
        sx[r*XSTRIDE + (c4 << 2) + (cc & 3)] = v;
    }
    __syncthreads();

    // ---- compute: each thread 8 wide x 2 tall
    const int tx = tid & 7;
    const int ty = tid >> 3;
    const int x0 = tx << 3;
    const int y0 = ty << 1;

    float acc0[8] = {0,0,0,0,0,0,0,0};
    float acc1[8] = {0,0,0,0,0,0,0,0};
    float krP[KS];

    #pragma unroll 1
    for (int ir = 0; ir < KS + 1; ++ir) {
        const int row  = y0 + ir;
        const int sbase = row * XSTRIDE;
        const int sw    = 3*((row >> 1) & 7);
        float xv[28];
        #pragma unroll
        for (int q = 0; q < 7; ++q) {
            int c4 = (x0 >> 2) + q + sw;
            if (c4 >= 24) c4 -= 24;
            const float4 v = *(const float4*)&sx[sbase + (c4 << 2)];
            xv[q*4+0] = v.x; xv[q*4+1] = v.y; xv[q*4+2] = v.z; xv[q*4+3] = v.w;
        }
        if (ir < KS) {
            float krN[24];
            #pragma unroll
            for (int q = 0; q < 6; ++q) {
                const float4 v = *(const float4*)&sk[ir*KSTRIDE + (q << 2)];
                krN[q*4+0] = v.x; krN[q*4+1] = v.y; krN[q*4+2] = v.z; krN[q*4+3] = v.w;
            }
            #pragma unroll
            for (int j = 0; j < KS; ++j) {
                #pragma unroll
                for (int q = 0; q < 8; ++q)
                    acc0[q] = fmaf(krN[j], xv[j+q], acc0[q]);
            }
            if (ir > 0) {
                #pragma unroll
                for (int j = 0; j < KS; ++j) {
                    #pragma unroll
                    for (int q = 0; q < 8; ++q)
                        acc1[q] = fmaf(krP[j], xv[j+q], acc1[q]);
                }
            }
            #pragma unroll
            for (int j = 0; j < KS; ++j) krP[j] = krN[j];
        } else {
            // ir == KS: last tap row for the second output row only
            #pragma unroll
            for (int j = 0; j < KS; ++j) {
                #pragma unroll
                for (int q = 0; q < 8; ++q)
                    acc1[q] = fmaf(krP[j], xv[j+q], acc1[q]);
            }
        }
    }

    // ---- fan-out writes to all duplicate output channels
    const int oS = (3*k > 22*c) ? 3*k : 22*c;
    const int t1 = 3*k + 2, t2 = 22*c + 21;
    const int oE = (t1 < t2) ? t1 : t2;
    const int gy = by*TILE + y0;
    const int gx = bx*TILE + x0;
    for (int o = oS; o <= oE; ++o) {
        float* ob = out + ((size_t)(b*66 + o) * Hh + gy) * Ww + gx;
        *(float4*)&ob[0]      = make_float4(acc0[0], acc0[1], acc0[2], acc0[3]);
        *(float4*)&ob[4]      = make_float4(acc0[4], acc0[5], acc0[6], acc0[7]);
        *(float4*)&ob[Ww]     = make_float4(acc1[0], acc1[1], acc1[2], acc1[3]);
        *(float4*)&ob[Ww + 4] = make_float4(acc1[4], acc1[5], acc1[6], acc1[7]);
    }
}

extern "C" void kernel_launch(void* const* d_in, const int* in_sizes, int n_in,
                              void* d_out, int out_size, void* d_ws, size_t ws_size,
                              hipStream_t stream) {
    const float* x   = (const float*)d_in[0];
    const float* wgt = (const float*)d_in[1];
    const float* bw  = (const float*)d_in[2];
    float* out = (float*)d_out;
    dim3 grid(Ww/TILE, Hh/TILE, Bn*NPAIR);
    gcm_conv<<<grid, 256, 0, stream>>>(x, wgt, bw, out);
}